// Round 17
// baseline (406.795 us; speedup 1.0000x reference)
//
#include <hip/hip_runtime.h>
#include <hip/hip_bf16.h>

// ---------------------------------------------------------------------------
// Swin block ×2 + CrossAttnFFN. FP32 in/out, bf16 MFMA everywhere, fp32 accum.
// Round 17: round-16 config + 1-wave blocks for the syncless attention
//           kernels (ca_flash 2048x64, win_attn 4096x64) — lets the CU pack
//           12 waves/CU (VGPR limit) instead of 8 (block-granularity limit).
// ---------------------------------------------------------------------------

typedef unsigned short u16;
typedef u16  u16x4 __attribute__((ext_vector_type(4)));
typedef u16  u16x8 __attribute__((ext_vector_type(8)));
typedef short s16x8 __attribute__((ext_vector_type(8)));
typedef float f32x4 __attribute__((ext_vector_type(4)));
typedef unsigned int u32x4 __attribute__((ext_vector_type(4)));

#define LOG2E 1.4426950408889634f
#define SCALE_LOG2 0.25503480f   // (1/sqrt(32)) * log2(e)

static __device__ __forceinline__ float bf2f(u16 u) {
    union { unsigned int i; float f; } v; v.i = ((unsigned int)u) << 16; return v.f;
}
static __device__ __forceinline__ u16 f2bf(float f) {
    unsigned int x = __float_as_uint(f);
    unsigned int r = x + 0x7fffu + ((x >> 16) & 1u);   // RNE
    return (u16)(r >> 16);
}
static __device__ __forceinline__ unsigned int cvtpk(float a, float b) {
    unsigned int u;
    asm("v_cvt_pk_bf16_f32 %0, %1, %2" : "=v"(u) : "v"(a), "v"(b));
    return u;   // lo = bf16(a), hi = bf16(b)
}
static __device__ __forceinline__ void gld16(const u16* g, u16* l) {
    __builtin_amdgcn_global_load_lds(
        (const __attribute__((address_space(1))) unsigned int*)g,
        (__attribute__((address_space(3))) unsigned int*)l, 16, 0, 0);
}
#define EXP2F __builtin_amdgcn_exp2f

// ---------------------------------------------------------------------------
// fp32 -> bf16 weight/query conversion (one fused kernel).
// ---------------------------------------------------------------------------
__launch_bounds__(256)
__global__ void cvt_weights(const float* __restrict__ qkvw, const float* __restrict__ outw,
                            const float* __restrict__ f1w,  const float* __restrict__ f2w,
                            const float* __restrict__ cpq,  const float* __restrict__ cfc,
                            const float* __restrict__ cf1,  const float* __restrict__ cf2,
                            const float* __restrict__ qry,  u16* __restrict__ dst) {
    const int q = blockIdx.x * 256 + threadIdx.x;
    const int gid = q * 4;
    const float* s; int off;
    if      (gid <  393216) { s = qkvw; off = 0;       }
    else if (gid <  524288) { s = outw; off = 393216;  }
    else if (gid < 1048576) { s = f1w;  off = 524288;  }
    else if (gid < 1572864) { s = f2w;  off = 1048576; }
    else if (gid < 1638400) { s = cpq;  off = 1572864; }
    else if (gid < 1703936) { s = cfc;  off = 1638400; }
    else if (gid < 1835008) { s = cf1;  off = 1703936; }
    else if (gid < 1966080) { s = cf2;  off = 1835008; }
    else                    { s = qry;  off = 1966080; }
    float4 v = *(const float4*)(s + (gid - off));
    u16x4 o; o[0] = f2bf(v.x); o[1] = f2bf(v.y); o[2] = f2bf(v.z); o[3] = f2bf(v.w);
    *(u16x4*)(dst + gid) = o;
}

// ---------------------------------------------------------------------------
// Relative-position bias in MFMA C-fragment layout, PERMUTED key map,
// pre-scaled by log2(e).
// ---------------------------------------------------------------------------
__launch_bounds__(256)
__global__ void bias_frag_kernel(const float* __restrict__ rel, float* __restrict__ bfrag) {
    const int idx = blockIdx.x * 256 + threadIdx.x;      // 0..16383
    #pragma unroll
    for (int j = 0; j < 4; ++j) {
        const int i = idx * 4 + j;
        const int layer = i >> 15, h = (i >> 12) & 7, kt = (i >> 10) & 3,
                  qt = (i >> 8) & 3, lane = (i >> 2) & 63, jj = i & 3;
        const int key   = (kt >> 1) * 32 + 4 * (kt & 1) + 8 * (lane >> 4) + jj;
        const int query = qt * 16 + (lane & 15);
        const int dy = (query >> 3) - (key >> 3) + 7;
        const int dx = (query & 7)  - (key & 7)  + 7;
        bfrag[i] = rel[layer * 1800 + (dy * 15 + dx) * 8 + h] * LOG2E;
    }
}

// ---------------------------------------------------------------------------
// LayerNorm: one wave per row, C=256. fp32 in -> bf16 out.
// ---------------------------------------------------------------------------
__launch_bounds__(256)
__global__ void ln_kernel(const float* __restrict__ in, u16* __restrict__ out,
                          const float* __restrict__ g, const float* __restrict__ b,
                          int rows) {
    const int wave = threadIdx.x >> 6, lane = threadIdx.x & 63;
    const int row = blockIdx.x * 4 + wave;
    if (row >= rows) return;
    const int c = lane * 4;
    float4 v = *(const float4*)(in + (size_t)row * 256 + c);
    float s1 = v.x + v.y + v.z + v.w;
    float s2 = v.x*v.x + v.y*v.y + v.z*v.z + v.w*v.w;
    #pragma unroll
    for (int off = 32; off; off >>= 1) {
        s1 += __shfl_xor(s1, off);
        s2 += __shfl_xor(s2, off);
    }
    const float mean = s1 * (1.f/256.f);
    const float var  = s2 * (1.f/256.f) - mean*mean;
    const float rstd = rsqrtf(var + 1e-5f);
    float4 gg = *(const float4*)(g + c);
    float4 bb = *(const float4*)(b + c);
    u16x4 og;
    og[0] = f2bf((v.x-mean)*rstd*gg.x + bb.x);
    og[1] = f2bf((v.y-mean)*rstd*gg.y + bb.y);
    og[2] = f2bf((v.z-mean)*rstd*gg.z + bb.z);
    og[3] = f2bf((v.w-mean)*rstd*gg.w + bb.w);
    *(u16x4*)(out + (size_t)row * 256 + c) = og;
}

// ---------------------------------------------------------------------------
// 128x128 GEMM: linear LDS dest + global_load_lds(16B) with pre-swizzled
// global source slot, XOR-swizzled ds_read. XCD-aware block swizzle. BK=64.
// EPI: 2 +bias+fastgelu, 3 +bias+resid(f32), 7 qkv (+bias, scale q, v->vtbuf),
//      8 +bias+resid dual-write (f32 out + bf16 aux)
// ---------------------------------------------------------------------------
template<int EPI, bool F32O>
__launch_bounds__(256)
__global__ void gemm128(const u16* __restrict__ A, const u16* __restrict__ W,
                        const float* __restrict__ bias, const float* __restrict__ resid,
                        void* __restrict__ outv, u16* __restrict__ aux,
                        int M, int N, int K) {
    __shared__ u16 As[128 * 64];
    __shared__ u16 Bs[128 * 64];
    const int nx = gridDim.x;
    const int nwg = nx * gridDim.y;
    int bid = blockIdx.y * nx + blockIdx.x;
    bid = (bid & 7) * (nwg >> 3) + (bid >> 3);     // chunked XCD swizzle (T1)
    const int m0 = (bid / nx) * 128, n0 = (bid % nx) * 128;
    const int tid = threadIdx.x, lane = tid & 63, wave = tid >> 6;
    const int g = lane >> 4, c = lane & 15;
    const int wm = (wave >> 1) * 64, wn = (wave & 1) * 64;

    f32x4 acc[4][4];
    #pragma unroll
    for (int i = 0; i < 4; ++i)
        #pragma unroll
        for (int j = 0; j < 4; ++j) acc[i][j] = f32x4{0.f,0.f,0.f,0.f};

    const int srow = (lane >> 3);
    const int scol = ((lane & 7) ^ srow) * 8;      // pre-swizzled source slot
    const int cx = c & 7;                          // read-side XOR key
    for (int k0 = 0; k0 < K; k0 += 64) {
        #pragma unroll
        for (int i = 0; i < 4; ++i) {
            const int ch = wave * 4 + i;             // chunk 0..15 (8 rows each)
            const int r = ch * 8 + srow;
            gld16(&A[(size_t)(m0 + r) * K + k0 + scol], &As[ch * 512]);
            gld16(&W[(size_t)(n0 + r) * K + k0 + scol], &Bs[ch * 512]);
        }
        __syncthreads();
        #pragma unroll
        for (int kk = 0; kk < 64; kk += 32) {
            const int slot = (kk >> 3) + g;          // 0..7 across kk,g
            s16x8 af[4], bf_[4];
            #pragma unroll
            for (int mi = 0; mi < 4; ++mi)
                af[mi] = *(const s16x8*)&As[(wm + mi*16 + c) * 64 + (slot ^ cx) * 8];
            #pragma unroll
            for (int ni = 0; ni < 4; ++ni)
                bf_[ni] = *(const s16x8*)&Bs[(wn + ni*16 + c) * 64 + (slot ^ cx) * 8];
            #pragma unroll
            for (int mi = 0; mi < 4; ++mi)
                #pragma unroll
                for (int ni = 0; ni < 4; ++ni)
                    acc[mi][ni] = __builtin_amdgcn_mfma_f32_16x16x32_bf16(
                        af[mi], bf_[ni], acc[mi][ni], 0, 0, 0);
        }
        __syncthreads();
    }

    #pragma unroll
    for (int mi = 0; mi < 4; ++mi) {
        #pragma unroll
        for (int ni = 0; ni < 4; ++ni) {
            const int col = n0 + wn + ni*16 + c;
            if (EPI == 7 && col >= 512) {
                const int row0 = m0 + wm + mi*16 + g*4;
                const int bidx = row0 >> 14, y = (row0 >> 7) & 127, xx0 = row0 & 127;
                const int wini = (bidx*16 + (y>>3))*16 + (xx0>>3);
                const int key0 = ((y&7)<<3) | (xx0&7);
                const float bb2 = bias[col];
                u16x4 pv;
                #pragma unroll
                for (int j = 0; j < 4; ++j) pv[j] = f2bf(acc[mi][ni][j] + bb2);
                *(u16x4*)&aux[((size_t)wini*256 + (col-512))*64 + key0] = pv;
                continue;
            }
            #pragma unroll
            for (int j = 0; j < 4; ++j) {
                const int row = m0 + wm + mi*16 + g*4 + j;
                float v = acc[mi][ni][j];
                v += bias[col];
                if (EPI == 2) {
                    const float t = EXP2F(2.3022082f * fmaf(0.044715f * v, v * v, v));
                    v = v * t * __builtin_amdgcn_rcpf(t + 1.f);
                }
                if (EPI == 3 || EPI == 8) v += resid[(size_t)row * N + col];
                if (EPI == 8) {
                    ((float*)outv)[(size_t)row * N + col] = v;
                    aux[(size_t)row * N + col] = f2bf(v);
                    continue;
                }
                if (EPI == 7 && col < 256) v *= SCALE_LOG2;
                if (F32O) ((float*)outv)[(size_t)row * N + col] = v;
                else      ((u16*)outv)[(size_t)row * N + col]   = f2bf(v);
            }
        }
    }
}

// ---------------------------------------------------------------------------
// 64x64 GEMM (M=1024 CA GEMMs). EPI: 1 bias, 4 bias+relu, 5 bias+clip32,
// 6 softmax-log2-scale (no bias).
// ---------------------------------------------------------------------------
template<int EPI>
__launch_bounds__(256)
__global__ void gemm_bt(const u16* __restrict__ A, const u16* __restrict__ W,
                        const float* __restrict__ bias, u16* __restrict__ out,
                        int M, int N, int K) {
    __shared__ u16 As[64][72];
    __shared__ u16 Bs[64][72];
    const int m0 = blockIdx.y * 64;
    const int n0 = blockIdx.x * 64;
    const int tid = threadIdx.x;
    const int lane = tid & 63, wave = tid >> 6;
    const int wm = (wave >> 1) * 32, wn = (wave & 1) * 32;

    f32x4 acc[2][2];
    #pragma unroll
    for (int i = 0; i < 2; ++i)
        #pragma unroll
        for (int j = 0; j < 2; ++j) acc[i][j] = f32x4{0.f,0.f,0.f,0.f};

    for (int k0 = 0; k0 < K; k0 += 64) {
        #pragma unroll
        for (int rep = 0; rep < 2; ++rep) {
            int i = tid + rep * 256;
            int r = i >> 3, c = (i & 7) * 8;
            *(s16x8*)&As[r][c] = *(const s16x8*)&A[(size_t)(m0 + r) * K + k0 + c];
            *(s16x8*)&Bs[r][c] = *(const s16x8*)&W[(size_t)(n0 + r) * K + k0 + c];
        }
        __syncthreads();
        #pragma unroll
        for (int kk = 0; kk < 64; kk += 32) {
            s16x8 af[2], bfr[2];
            #pragma unroll
            for (int i = 0; i < 2; ++i) {
                af[i]  = *(const s16x8*)&As[wm + i*16 + (lane & 15)][kk + (lane >> 4) * 8];
                bfr[i] = *(const s16x8*)&Bs[wn + i*16 + (lane & 15)][kk + (lane >> 4) * 8];
            }
            #pragma unroll
            for (int mi = 0; mi < 2; ++mi)
                #pragma unroll
                for (int ni = 0; ni < 2; ++ni)
                    acc[mi][ni] = __builtin_amdgcn_mfma_f32_16x16x32_bf16(
                        af[mi], bfr[ni], acc[mi][ni], 0, 0, 0);
        }
        __syncthreads();
    }

    #pragma unroll
    for (int mi = 0; mi < 2; ++mi) {
        #pragma unroll
        for (int ni = 0; ni < 2; ++ni) {
            const int col = n0 + wn + ni*16 + (lane & 15);
            #pragma unroll
            for (int j = 0; j < 4; ++j) {
                const int row = m0 + wm + mi*16 + (lane >> 4)*4 + j;
                float v = acc[mi][ni][j];
                if (EPI >= 1 && EPI <= 5) v += bias[col];
                if (EPI == 4) v = fmaxf(v, 0.f);
                if (EPI == 5) v = fminf(fmaxf(v, -32.f), 32.f);
                if (EPI == 6) v *= SCALE_LOG2;
                out[(size_t)row * N + col] = f2bf(v);
            }
        }
    }
}

// ---------------------------------------------------------------------------
// MFMA windowed self-attention, shuffle-free, max-free softmax.
// 1-wave blocks (no LDS, no barriers).
// ---------------------------------------------------------------------------
__launch_bounds__(64)
__global__ void win_attn(const u16* __restrict__ qkv, const u16* __restrict__ vtbuf,
                         const float* __restrict__ bfrag, u16* __restrict__ o,
                         int layer) {
    const int wid = blockIdx.x;                            // 0..4095
    const int lane = threadIdx.x;
    const int h = wid & 7, win = wid >> 3;
    const int b = win >> 8, wy = (win >> 4) & 15, wx = win & 15;
    const int g = lane >> 4, c = lane & 15;
    const size_t rowbase = (size_t)b * 16384 + (size_t)wy * 8 * 128 + wx * 8;

    s16x8 qf[4], kf[4];
    #pragma unroll
    for (int qt = 0; qt < 4; ++qt) {
        const int t = qt * 16 + c;
        qf[qt] = *(const s16x8*)&qkv[(rowbase + (size_t)(t >> 3) * 128 + (t & 7)) * 768
                                     + h * 32 + g * 8];
    }
    const int kp0 = 8 * (c >> 2) + (c & 3);       // permuted key row for this lane
    #pragma unroll
    for (int kt = 0; kt < 4; ++kt) {
        const int t = (kt >> 1) * 32 + 4 * (kt & 1) + kp0;
        kf[kt] = *(const s16x8*)&qkv[(rowbase + (size_t)(t >> 3) * 128 + (t & 7)) * 768
                                     + 256 + h * 32 + g * 8];
    }

    const float* bb = bfrag + (size_t)((layer * 8 + h) * 16) * 256;
    f32x4 st[4][4];
    #pragma unroll
    for (int kt = 0; kt < 4; ++kt)
        #pragma unroll
        for (int qt = 0; qt < 4; ++qt)
            st[kt][qt] = *(const f32x4*)&bb[(kt * 4 + qt) * 256 + lane * 4];
    #pragma unroll
    for (int kt = 0; kt < 4; ++kt)
        #pragma unroll
        for (int qt = 0; qt < 4; ++qt)
            st[kt][qt] = __builtin_amdgcn_mfma_f32_16x16x32_bf16(
                kf[kt], qf[qt], st[kt][qt], 0, 0, 0);

    float linv[4];
    #pragma unroll
    for (int qt = 0; qt < 4; ++qt) {
        float sum = 0.f;
        #pragma unroll
        for (int kt = 0; kt < 4; ++kt)
            #pragma unroll
            for (int j = 0; j < 4; ++j) {
                const float p = EXP2F(st[kt][qt][j]);
                st[kt][qt][j] = p;
                sum += p;
            }
        sum += __shfl_xor(sum, 16);
        sum += __shfl_xor(sum, 32);
        linv[qt] = 1.f / sum;
    }

    const u16* vb = vtbuf + ((size_t)win * 256 + h * 32) * 64;
    s16x8 vf[2][2];
    #pragma unroll
    for (int dt = 0; dt < 2; ++dt)
        #pragma unroll
        for (int ks = 0; ks < 2; ++ks)
            vf[dt][ks] = *(const s16x8*)&vb[(size_t)(dt * 16 + c) * 64 + ks * 32 + g * 8];

    f32x4 acc[4][2];
    #pragma unroll
    for (int i = 0; i < 4; ++i)
        #pragma unroll
        for (int j = 0; j < 2; ++j) acc[i][j] = f32x4{0.f,0.f,0.f,0.f};

    #pragma unroll
    for (int qt = 0; qt < 4; ++qt) {
        #pragma unroll
        for (int ks = 0; ks < 2; ++ks) {
            u32x4 w;
            w[0] = cvtpk(st[2*ks][qt][0],   st[2*ks][qt][1]);
            w[1] = cvtpk(st[2*ks][qt][2],   st[2*ks][qt][3]);
            w[2] = cvtpk(st[2*ks+1][qt][0], st[2*ks+1][qt][1]);
            w[3] = cvtpk(st[2*ks+1][qt][2], st[2*ks+1][qt][3]);
            const s16x8 pfrag = __builtin_bit_cast(s16x8, w);
            acc[qt][0] = __builtin_amdgcn_mfma_f32_16x16x32_bf16(pfrag, vf[0][ks], acc[qt][0], 0,0,0);
            acc[qt][1] = __builtin_amdgcn_mfma_f32_16x16x32_bf16(pfrag, vf[1][ks], acc[qt][1], 0,0,0);
        }
    }

    #pragma unroll
    for (int qt = 0; qt < 4; ++qt)
        #pragma unroll
        for (int dt = 0; dt < 2; ++dt)
            #pragma unroll
            for (int j = 0; j < 4; ++j) {
                const int t = qt * 16 + g * 4 + j;
                o[(rowbase + (size_t)(t >> 3) * 128 + (t & 7)) * 256
                  + h * 32 + dt * 16 + c] = f2bf(acc[qt][dt][j] * linv[qt]);
            }
}

// ---------------------------------------------------------------------------
// Transpose: xbT[b][c][n] = xb[b][n][c].
// ---------------------------------------------------------------------------
__launch_bounds__(256)
__global__ void tr_kernel(const u16* __restrict__ src, u16* __restrict__ dst) {
    __shared__ u16 T[64][72];
    const int b = blockIdx.z;
    const int n0 = blockIdx.x * 64, c0 = blockIdx.y * 64;
    const int r = threadIdx.x >> 3, cc = (threadIdx.x & 7) * 8;
    const u16* S = src + (size_t)b * 16384 * 256;
    u16* D = dst + (size_t)b * 256 * 16384;
    #pragma unroll
    for (int rr = 0; rr < 64; rr += 32)
        *(u16x8*)&T[r + rr][cc] = *(const u16x8*)&S[(size_t)(n0 + r + rr) * 256 + c0 + cc];
    __syncthreads();
    #pragma unroll
    for (int rr = 0; rr < 64; rr += 32) {
        u16x8 v;
        #pragma unroll
        for (int k2 = 0; k2 < 8; ++k2) v[k2] = T[cc + k2][r + rr];
        *(u16x8*)&D[(size_t)(c0 + r + rr) * 16384 + n0 + cc] = v;
    }
}

// ---------------------------------------------------------------------------
// MFMA flash cross-attention: max-free softmax, denominator via ones-MFMA,
// 128 queries/wave, KSPLIT=32. 1-wave blocks (no LDS, no barriers).
// ---------------------------------------------------------------------------
__launch_bounds__(64)
__global__ void ca_flash(const u16* __restrict__ qb, const u16* __restrict__ xb,
                         const u16* __restrict__ xbT, float* __restrict__ pbuf) {
    const int wid = blockIdx.x;                // 0..2047
    const int lane = threadIdx.x;
    const int ks = wid & 31, qt = (wid >> 5) & 3, h = (wid >> 7) & 7, b = wid >> 10;
    const int g = lane >> 4, c = lane & 15;
    const int kp0 = 8 * (c >> 2) + (c & 3);    // permuted key row for this lane

    s16x8 qf[8];
    #pragma unroll
    for (int nt = 0; nt < 8; ++nt) {
        const int q = qt * 128 + nt * 16 + c;
        qf[nt] = *(const s16x8*)&qb[((size_t)q * 2 + b) * 256 + h * 32 + g * 8];
    }
    const u16* Kb = xb  + (size_t)b * 16384 * 256 + h * 32;
    const u16* Vb = xbT + (size_t)b * 256 * 16384 + (size_t)(h * 32) * 16384;

    s16x8 ones;
    #pragma unroll
    for (int j = 0; j < 8; ++j) ones[j] = (short)0x3F80;   // bf16 1.0

    f32x4 acc[2][8];    // [d-tile][q-subtile]
    f32x4 accl[8];      // denominator rows per q-subtile
    #pragma unroll
    for (int j = 0; j < 8; ++j) {
        acc[0][j] = f32x4{0.f,0.f,0.f,0.f};
        acc[1][j] = f32x4{0.f,0.f,0.f,0.f};
        accl[j]   = f32x4{0.f,0.f,0.f,0.f};
    }

    const int base = ks * 512;
    const f32x4 zero = f32x4{0.f, 0.f, 0.f, 0.f};
    for (int step = 0; step < 16; ++step) {
        const int n0 = base + step * 32;
        const s16x8 kf0 = *(const s16x8*)&Kb[(size_t)(n0 + kp0) * 256 + g * 8];
        const s16x8 kf1 = *(const s16x8*)&Kb[(size_t)(n0 + kp0 + 4) * 256 + g * 8];
        const s16x8 vf0 = *(const s16x8*)&Vb[(size_t)c * 16384 + n0 + g * 8];
        const s16x8 vf1 = *(const s16x8*)&Vb[(size_t)(16 + c) * 16384 + n0 + g * 8];
        #pragma unroll
        for (int nt = 0; nt < 8; ++nt) {
            const f32x4 sa = __builtin_amdgcn_mfma_f32_16x16x32_bf16(kf0, qf[nt], zero, 0, 0, 0);
            const f32x4 sb = __builtin_amdgcn_mfma_f32_16x16x32_bf16(kf1, qf[nt], zero, 0, 0, 0);
            u32x4 w;
            w[0] = cvtpk(EXP2F(sa[0]), EXP2F(sa[1]));
            w[1] = cvtpk(EXP2F(sa[2]), EXP2F(sa[3]));
            w[2] = cvtpk(EXP2F(sb[0]), EXP2F(sb[1]));
            w[3] = cvtpk(EXP2F(sb[2]), EXP2F(sb[3]));
            const s16x8 pf = __builtin_bit_cast(s16x8, w);
            acc[0][nt] = __builtin_amdgcn_mfma_f32_16x16x32_bf16(vf0, pf, acc[0][nt], 0, 0, 0);
            acc[1][nt] = __builtin_amdgcn_mfma_f32_16x16x32_bf16(vf1, pf, acc[1][nt], 0, 0, 0);
            accl[nt]   = __builtin_amdgcn_mfma_f32_16x16x32_bf16(ones, pf, accl[nt], 0, 0, 0);
        }
    }

    // pbuf wave record (4224 f32): [0..127] = l per query, [128..4223] = O^T
    float* P = pbuf + (size_t)wid * 4224;
    if (g == 0) {
        #pragma unroll
        for (int nt = 0; nt < 8; ++nt)
            P[nt * 16 + c] = accl[nt][0];
    }
    #pragma unroll
    for (int mi = 0; mi < 2; ++mi)
        #pragma unroll
        for (int nt = 0; nt < 8; ++nt)
            *(f32x4*)&P[128 + (c + 16*nt) * 32 + 16*mi + g*4] = acc[mi][nt];
}

// ---------------------------------------------------------------------------
// Merge 32 key-split partials: plain sums (no exp, no max).
// ---------------------------------------------------------------------------
__launch_bounds__(256)
__global__ void ca_merge(const float* __restrict__ pbuf, u16* __restrict__ ctx) {
    const int wave = threadIdx.x >> 6, lane = threadIdx.x & 63;
    const int sub = lane >> 5, d = lane & 31;
    const int rowid = blockIdx.x * 8 + wave * 2 + sub;     // 0..8191
    const int t = rowid & 511, h = (rowid >> 9) & 7, b = rowid >> 12;
    const int qt = t >> 7, qq = t & 127;
    const size_t w0 = (size_t)((b * 8 + h) * 4 + qt) * 32;
    float L = 0.f, o = 0.f;
    #pragma unroll
    for (int i = 0; i < 32; ++i) {
        L += pbuf[(w0 + i) * 4224 + qq];
        o += pbuf[(w0 + i) * 4224 + 128 + qq * 32 + d];
    }
    ctx[((size_t)b * 512 + t) * 256 + h * 32 + d] = f2bf(o / L);
}

// ---------------------------------------------------------------------------
// Final: out = LN(query + ctx^T).
// ---------------------------------------------------------------------------
__launch_bounds__(256)
__global__ void final_ln(const float* __restrict__ query, const u16* __restrict__ ctx4,
                         const float* __restrict__ g, const float* __restrict__ b,
                         float* __restrict__ out) {
    const int wave = threadIdx.x >> 6, lane = threadIdx.x & 63;
    const int row = blockIdx.x * 4 + wave;        // 0..1023 = t*2+bb
    const int t = row >> 1, bb = row & 1;
    const int c = lane * 4;
    float4 rq = *(const float4*)(query + (size_t)row * 256 + c);
    u16x4 rc = *(const u16x4*)(ctx4 + ((size_t)bb * 512 + t) * 256 + c);
    float x0 = rq.x + bf2f(rc[0]);
    float x1 = rq.y + bf2f(rc[1]);
    float x2 = rq.z + bf2f(rc[2]);
    float x3 = rq.w + bf2f(rc[3]);
    float s1 = x0 + x1 + x2 + x3;
    float s2 = x0*x0 + x1*x1 + x2*x2 + x3*x3;
    #pragma unroll
    for (int off = 32; off; off >>= 1) {
        s1 += __shfl_xor(s1, off);
        s2 += __shfl_xor(s2, off);
    }
    const float mean = s1 * (1.f/256.f);
    const float var  = s2 * (1.f/256.f) - mean*mean;
    const float rstd = rsqrtf(var + 1e-5f);
    float4 gg = *(const float4*)(g + c);
    float4 bv = *(const float4*)(b + c);
    float4 og;
    og.x = (x0-mean)*rstd*gg.x + bv.x;
    og.y = (x1-mean)*rstd*gg.y + bv.y;
    og.z = (x2-mean)*rstd*gg.z + bv.z;
    og.w = (x3-mean)*rstd*gg.w + bv.w;
    *(float4*)(out + (size_t)row * 256 + c) = og;
}

// ---------------------------------------------------------------------------

extern "C" void kernel_launch(void* const* d_in, const int* in_sizes, int n_in,
                              void* d_out, int out_size, void* d_ws, size_t ws_size,
                              hipStream_t stream) {
    const float* x_in  = (const float*)d_in[0];
    const float* query = (const float*)d_in[1];
    const float* n1_g  = (const float*)d_in[2];
    const float* n1_b  = (const float*)d_in[3];
    const float* qkv_w = (const float*)d_in[4];
    const float* qkv_b = (const float*)d_in[5];
    const float* out_w = (const float*)d_in[6];
    const float* out_b = (const float*)d_in[7];
    const float* rel   = (const float*)d_in[8];
    const float* n2_g  = (const float*)d_in[9];
    const float* n2_b  = (const float*)d_in[10];
    const float* fc1_w = (const float*)d_in[11];
    const float* fc1_b = (const float*)d_in[12];
    const float* fc2_w = (const float*)d_in[13];
    const float* fc2_b = (const float*)d_in[14];
    const float* can_g = (const float*)d_in[15];
    const float* can_b = (const float*)d_in[16];
    const float* cpq_w = (const float*)d_in[17];
    const float* cfc_w = (const float*)d_in[18];
    const float* cfc_b = (const float*)d_in[19];
    const float* cf1_w = (const float*)d_in[20];
    const float* cf1_b = (const float*)d_in[21];
    const float* cf2_w = (const float*)d_in[22];
    const float* cf2_b = (const float*)d_in[23];

    const int M = 32768;   // 2 * 128 * 128 tokens

    char* w = (char*)d_ws;
    float* xs  = (float*)w;  w += (size_t)M * 256 * 4;        // fp32 residual stream
    u16* hbuf  = (u16*)w;    w += (size_t)M * 256 * 2;        // bf16 LN/attn out
    u16* big   = (u16*)w;    w += (size_t)M * 1024 * 2;       // bf16 qkv / mlp hidden
    u16* arena = (u16*)w;    w += (size_t)2228224 * 2;        // bf16 weights + query
    u16* qbuf  = (u16*)w;    w += 524288;
    u16* ctx1  = (u16*)w;    w += 524288;
    u16* ctx2  = (u16*)w;    w += 524288;
    u16* ctx3  = (u16*)w;    w += 1048576;
    u16* ctx4  = (u16*)w;    w += 524288;
    u16* xb    = (u16*)w;    w += (size_t)M * 256 * 2;        // bf16 copy of final xs
    float* bfragb = (float*)w; w += 65536 * 4;                // bias C-fragments

    u16* vtbuf = big + (size_t)M * 768;                       // 16 MB (qkv tail)
    u16*   xbT  = big;                                        // (2,256,16384) 16 MB
    float* pbuf = (float*)(big + 8388608);                    // 2048 * 4224 f32 = 34.6 MB

    u16* wq   = arena;
    u16* wo   = arena + 393216;
    u16* wf1  = arena + 524288;
    u16* wf2  = arena + 1048576;
    u16* wcpq = arena + 1572864;
    u16* wcfc = arena + 1638400;
    u16* wcf1 = arena + 1703936;
    u16* wcf2 = arena + 1835008;
    u16* qcvt = arena + 1966080;

    cvt_weights<<<2176, 256, 0, stream>>>(qkv_w, out_w, fc1_w, fc2_w, cpq_w,
                                          cfc_w, cf1_w, cf2_w, query, arena);
    bias_frag_kernel<<<64, 256, 0, stream>>>(rel, bfragb);

    for (int i = 0; i < 2; ++i) {
        const float* src = (i == 0) ? x_in : xs;   // layer-0 reads input directly
        ln_kernel<<<M/4, 256, 0, stream>>>(src, hbuf, n1_g + i*256, n1_b + i*256, M);
        gemm128<7,false><<<dim3(6,256), 256, 0, stream>>>(
            hbuf, wq + (size_t)i*768*256, qkv_b + i*768, nullptr, big, vtbuf, M, 768, 256);
        win_attn<<<4096, 64, 0, stream>>>(big, vtbuf, bfragb, hbuf, i);
        gemm128<3,true><<<dim3(2,256), 256, 0, stream>>>(
            hbuf, wo + (size_t)i*65536, out_b + i*256, src, xs, nullptr, M, 256, 256);
        ln_kernel<<<M/4, 256, 0, stream>>>(xs, hbuf, n2_g + i*256, n2_b + i*256, M);
        gemm128<2,false><<<dim3(8,256), 256, 0, stream>>>(
            hbuf, wf1 + (size_t)i*262144, fc1_b + i*1024, nullptr, big, nullptr, M, 1024, 256);
        if (i == 0)
            gemm128<3,true><<<dim3(2,256), 256, 0, stream>>>(
                big, wf2, fc2_b, xs, xs, nullptr, M, 256, 1024);
        else
            gemm128<8,true><<<dim3(2,256), 256, 0, stream>>>(
                big, wf2 + 262144, fc2_b + 256, xs, xs, xb, M, 256, 1024);
    }

    // ---- cross-attention ----
    tr_kernel<<<dim3(256, 4, 2), 256, 0, stream>>>(xb, xbT);
    gemm_bt<6><<<dim3(4, 16), 256, 0, stream>>>(qcvt, wcpq, nullptr, qbuf, 1024, 256, 256);
    ca_flash<<<2048, 64, 0, stream>>>(qbuf, xb, xbT, pbuf);
    ca_merge<<<1024, 256, 0, stream>>>(pbuf, ctx1);
    gemm_bt<5><<<dim3(4, 16), 256, 0, stream>>>(ctx1, wcfc, cfc_b, ctx2, 1024, 256, 256);
    gemm_bt<4><<<dim3(8, 16), 256, 0, stream>>>(ctx2, wcf1, cf1_b, ctx3, 1024, 512, 256);
    gemm_bt<1><<<dim3(4, 16), 256, 0, stream>>>(ctx3, wcf2, cf2_b, ctx4, 1024, 256, 512);
    final_ln<<<256, 256, 0, stream>>>(query, ctx4, can_g, can_b, (float*)d_out);

    (void)in_sizes; (void)n_in; (void)out_size; (void)ws_size;
}

// Round 18
// 400.837 us; speedup vs baseline: 1.0149x; 1.0149x over previous
//
#include <hip/hip_runtime.h>
#include <hip/hip_bf16.h>

// ---------------------------------------------------------------------------
// Swin block ×2 + CrossAttnFFN. FP32 in/out, bf16 MFMA everywhere, fp32 accum.
// Round 18: ca_flash keeps 1-wave blocks (residency win, r17);
//           win_attn reverts to 256-thread blocks (dispatch-overhead regime).
// ---------------------------------------------------------------------------

typedef unsigned short u16;
typedef u16  u16x4 __attribute__((ext_vector_type(4)));
typedef u16  u16x8 __attribute__((ext_vector_type(8)));
typedef short s16x8 __attribute__((ext_vector_type(8)));
typedef float f32x4 __attribute__((ext_vector_type(4)));
typedef unsigned int u32x4 __attribute__((ext_vector_type(4)));

#define LOG2E 1.4426950408889634f
#define SCALE_LOG2 0.25503480f   // (1/sqrt(32)) * log2(e)

static __device__ __forceinline__ float bf2f(u16 u) {
    union { unsigned int i; float f; } v; v.i = ((unsigned int)u) << 16; return v.f;
}
static __device__ __forceinline__ u16 f2bf(float f) {
    unsigned int x = __float_as_uint(f);
    unsigned int r = x + 0x7fffu + ((x >> 16) & 1u);   // RNE
    return (u16)(r >> 16);
}
static __device__ __forceinline__ unsigned int cvtpk(float a, float b) {
    unsigned int u;
    asm("v_cvt_pk_bf16_f32 %0, %1, %2" : "=v"(u) : "v"(a), "v"(b));
    return u;   // lo = bf16(a), hi = bf16(b)
}
static __device__ __forceinline__ void gld16(const u16* g, u16* l) {
    __builtin_amdgcn_global_load_lds(
        (const __attribute__((address_space(1))) unsigned int*)g,
        (__attribute__((address_space(3))) unsigned int*)l, 16, 0, 0);
}
#define EXP2F __builtin_amdgcn_exp2f

// ---------------------------------------------------------------------------
// fp32 -> bf16 weight/query conversion (one fused kernel).
// ---------------------------------------------------------------------------
__launch_bounds__(256)
__global__ void cvt_weights(const float* __restrict__ qkvw, const float* __restrict__ outw,
                            const float* __restrict__ f1w,  const float* __restrict__ f2w,
                            const float* __restrict__ cpq,  const float* __restrict__ cfc,
                            const float* __restrict__ cf1,  const float* __restrict__ cf2,
                            const float* __restrict__ qry,  u16* __restrict__ dst) {
    const int q = blockIdx.x * 256 + threadIdx.x;
    const int gid = q * 4;
    const float* s; int off;
    if      (gid <  393216) { s = qkvw; off = 0;       }
    else if (gid <  524288) { s = outw; off = 393216;  }
    else if (gid < 1048576) { s = f1w;  off = 524288;  }
    else if (gid < 1572864) { s = f2w;  off = 1048576; }
    else if (gid < 1638400) { s = cpq;  off = 1572864; }
    else if (gid < 1703936) { s = cfc;  off = 1638400; }
    else if (gid < 1835008) { s = cf1;  off = 1703936; }
    else if (gid < 1966080) { s = cf2;  off = 1835008; }
    else                    { s = qry;  off = 1966080; }
    float4 v = *(const float4*)(s + (gid - off));
    u16x4 o; o[0] = f2bf(v.x); o[1] = f2bf(v.y); o[2] = f2bf(v.z); o[3] = f2bf(v.w);
    *(u16x4*)(dst + gid) = o;
}

// ---------------------------------------------------------------------------
// Relative-position bias in MFMA C-fragment layout, PERMUTED key map,
// pre-scaled by log2(e).
// ---------------------------------------------------------------------------
__launch_bounds__(256)
__global__ void bias_frag_kernel(const float* __restrict__ rel, float* __restrict__ bfrag) {
    const int idx = blockIdx.x * 256 + threadIdx.x;      // 0..16383
    #pragma unroll
    for (int j = 0; j < 4; ++j) {
        const int i = idx * 4 + j;
        const int layer = i >> 15, h = (i >> 12) & 7, kt = (i >> 10) & 3,
                  qt = (i >> 8) & 3, lane = (i >> 2) & 63, jj = i & 3;
        const int key   = (kt >> 1) * 32 + 4 * (kt & 1) + 8 * (lane >> 4) + jj;
        const int query = qt * 16 + (lane & 15);
        const int dy = (query >> 3) - (key >> 3) + 7;
        const int dx = (query & 7)  - (key & 7)  + 7;
        bfrag[i] = rel[layer * 1800 + (dy * 15 + dx) * 8 + h] * LOG2E;
    }
}

// ---------------------------------------------------------------------------
// LayerNorm: one wave per row, C=256. fp32 in -> bf16 out.
// ---------------------------------------------------------------------------
__launch_bounds__(256)
__global__ void ln_kernel(const float* __restrict__ in, u16* __restrict__ out,
                          const float* __restrict__ g, const float* __restrict__ b,
                          int rows) {
    const int wave = threadIdx.x >> 6, lane = threadIdx.x & 63;
    const int row = blockIdx.x * 4 + wave;
    if (row >= rows) return;
    const int c = lane * 4;
    float4 v = *(const float4*)(in + (size_t)row * 256 + c);
    float s1 = v.x + v.y + v.z + v.w;
    float s2 = v.x*v.x + v.y*v.y + v.z*v.z + v.w*v.w;
    #pragma unroll
    for (int off = 32; off; off >>= 1) {
        s1 += __shfl_xor(s1, off);
        s2 += __shfl_xor(s2, off);
    }
    const float mean = s1 * (1.f/256.f);
    const float var  = s2 * (1.f/256.f) - mean*mean;
    const float rstd = rsqrtf(var + 1e-5f);
    float4 gg = *(const float4*)(g + c);
    float4 bb = *(const float4*)(b + c);
    u16x4 og;
    og[0] = f2bf((v.x-mean)*rstd*gg.x + bb.x);
    og[1] = f2bf((v.y-mean)*rstd*gg.y + bb.y);
    og[2] = f2bf((v.z-mean)*rstd*gg.z + bb.z);
    og[3] = f2bf((v.w-mean)*rstd*gg.w + bb.w);
    *(u16x4*)(out + (size_t)row * 256 + c) = og;
}

// ---------------------------------------------------------------------------
// 128x128 GEMM: linear LDS dest + global_load_lds(16B) with pre-swizzled
// global source slot, XOR-swizzled ds_read. XCD-aware block swizzle. BK=64.
// EPI: 2 +bias+fastgelu, 3 +bias+resid(f32), 7 qkv (+bias, scale q, v->vtbuf),
//      8 +bias+resid dual-write (f32 out + bf16 aux)
// ---------------------------------------------------------------------------
template<int EPI, bool F32O>
__launch_bounds__(256)
__global__ void gemm128(const u16* __restrict__ A, const u16* __restrict__ W,
                        const float* __restrict__ bias, const float* __restrict__ resid,
                        void* __restrict__ outv, u16* __restrict__ aux,
                        int M, int N, int K) {
    __shared__ u16 As[128 * 64];
    __shared__ u16 Bs[128 * 64];
    const int nx = gridDim.x;
    const int nwg = nx * gridDim.y;
    int bid = blockIdx.y * nx + blockIdx.x;
    bid = (bid & 7) * (nwg >> 3) + (bid >> 3);     // chunked XCD swizzle (T1)
    const int m0 = (bid / nx) * 128, n0 = (bid % nx) * 128;
    const int tid = threadIdx.x, lane = tid & 63, wave = tid >> 6;
    const int g = lane >> 4, c = lane & 15;
    const int wm = (wave >> 1) * 64, wn = (wave & 1) * 64;

    f32x4 acc[4][4];
    #pragma unroll
    for (int i = 0; i < 4; ++i)
        #pragma unroll
        for (int j = 0; j < 4; ++j) acc[i][j] = f32x4{0.f,0.f,0.f,0.f};

    const int srow = (lane >> 3);
    const int scol = ((lane & 7) ^ srow) * 8;      // pre-swizzled source slot
    const int cx = c & 7;                          // read-side XOR key
    for (int k0 = 0; k0 < K; k0 += 64) {
        #pragma unroll
        for (int i = 0; i < 4; ++i) {
            const int ch = wave * 4 + i;             // chunk 0..15 (8 rows each)
            const int r = ch * 8 + srow;
            gld16(&A[(size_t)(m0 + r) * K + k0 + scol], &As[ch * 512]);
            gld16(&W[(size_t)(n0 + r) * K + k0 + scol], &Bs[ch * 512]);
        }
        __syncthreads();
        #pragma unroll
        for (int kk = 0; kk < 64; kk += 32) {
            const int slot = (kk >> 3) + g;          // 0..7 across kk,g
            s16x8 af[4], bf_[4];
            #pragma unroll
            for (int mi = 0; mi < 4; ++mi)
                af[mi] = *(const s16x8*)&As[(wm + mi*16 + c) * 64 + (slot ^ cx) * 8];
            #pragma unroll
            for (int ni = 0; ni < 4; ++ni)
                bf_[ni] = *(const s16x8*)&Bs[(wn + ni*16 + c) * 64 + (slot ^ cx) * 8];
            #pragma unroll
            for (int mi = 0; mi < 4; ++mi)
                #pragma unroll
                for (int ni = 0; ni < 4; ++ni)
                    acc[mi][ni] = __builtin_amdgcn_mfma_f32_16x16x32_bf16(
                        af[mi], bf_[ni], acc[mi][ni], 0, 0, 0);
        }
        __syncthreads();
    }

    #pragma unroll
    for (int mi = 0; mi < 4; ++mi) {
        #pragma unroll
        for (int ni = 0; ni < 4; ++ni) {
            const int col = n0 + wn + ni*16 + c;
            if (EPI == 7 && col >= 512) {
                const int row0 = m0 + wm + mi*16 + g*4;
                const int bidx = row0 >> 14, y = (row0 >> 7) & 127, xx0 = row0 & 127;
                const int wini = (bidx*16 + (y>>3))*16 + (xx0>>3);
                const int key0 = ((y&7)<<3) | (xx0&7);
                const float bb2 = bias[col];
                u16x4 pv;
                #pragma unroll
                for (int j = 0; j < 4; ++j) pv[j] = f2bf(acc[mi][ni][j] + bb2);
                *(u16x4*)&aux[((size_t)wini*256 + (col-512))*64 + key0] = pv;
                continue;
            }
            #pragma unroll
            for (int j = 0; j < 4; ++j) {
                const int row = m0 + wm + mi*16 + g*4 + j;
                float v = acc[mi][ni][j];
                v += bias[col];
                if (EPI == 2) {
                    const float t = EXP2F(2.3022082f * fmaf(0.044715f * v, v * v, v));
                    v = v * t * __builtin_amdgcn_rcpf(t + 1.f);
                }
                if (EPI == 3 || EPI == 8) v += resid[(size_t)row * N + col];
                if (EPI == 8) {
                    ((float*)outv)[(size_t)row * N + col] = v;
                    aux[(size_t)row * N + col] = f2bf(v);
                    continue;
                }
                if (EPI == 7 && col < 256) v *= SCALE_LOG2;
                if (F32O) ((float*)outv)[(size_t)row * N + col] = v;
                else      ((u16*)outv)[(size_t)row * N + col]   = f2bf(v);
            }
        }
    }
}

// ---------------------------------------------------------------------------
// 64x64 GEMM (M=1024 CA GEMMs). EPI: 1 bias, 4 bias+relu, 5 bias+clip32,
// 6 softmax-log2-scale (no bias).
// ---------------------------------------------------------------------------
template<int EPI>
__launch_bounds__(256)
__global__ void gemm_bt(const u16* __restrict__ A, const u16* __restrict__ W,
                        const float* __restrict__ bias, u16* __restrict__ out,
                        int M, int N, int K) {
    __shared__ u16 As[64][72];
    __shared__ u16 Bs[64][72];
    const int m0 = blockIdx.y * 64;
    const int n0 = blockIdx.x * 64;
    const int tid = threadIdx.x;
    const int lane = tid & 63, wave = tid >> 6;
    const int wm = (wave >> 1) * 32, wn = (wave & 1) * 32;

    f32x4 acc[2][2];
    #pragma unroll
    for (int i = 0; i < 2; ++i)
        #pragma unroll
        for (int j = 0; j < 2; ++j) acc[i][j] = f32x4{0.f,0.f,0.f,0.f};

    for (int k0 = 0; k0 < K; k0 += 64) {
        #pragma unroll
        for (int rep = 0; rep < 2; ++rep) {
            int i = tid + rep * 256;
            int r = i >> 3, c = (i & 7) * 8;
            *(s16x8*)&As[r][c] = *(const s16x8*)&A[(size_t)(m0 + r) * K + k0 + c];
            *(s16x8*)&Bs[r][c] = *(const s16x8*)&W[(size_t)(n0 + r) * K + k0 + c];
        }
        __syncthreads();
        #pragma unroll
        for (int kk = 0; kk < 64; kk += 32) {
            s16x8 af[2], bfr[2];
            #pragma unroll
            for (int i = 0; i < 2; ++i) {
                af[i]  = *(const s16x8*)&As[wm + i*16 + (lane & 15)][kk + (lane >> 4) * 8];
                bfr[i] = *(const s16x8*)&Bs[wn + i*16 + (lane & 15)][kk + (lane >> 4) * 8];
            }
            #pragma unroll
            for (int mi = 0; mi < 2; ++mi)
                #pragma unroll
                for (int ni = 0; ni < 2; ++ni)
                    acc[mi][ni] = __builtin_amdgcn_mfma_f32_16x16x32_bf16(
                        af[mi], bfr[ni], acc[mi][ni], 0, 0, 0);
        }
        __syncthreads();
    }

    #pragma unroll
    for (int mi = 0; mi < 2; ++mi) {
        #pragma unroll
        for (int ni = 0; ni < 2; ++ni) {
            const int col = n0 + wn + ni*16 + (lane & 15);
            #pragma unroll
            for (int j = 0; j < 4; ++j) {
                const int row = m0 + wm + mi*16 + (lane >> 4)*4 + j;
                float v = acc[mi][ni][j];
                if (EPI >= 1 && EPI <= 5) v += bias[col];
                if (EPI == 4) v = fmaxf(v, 0.f);
                if (EPI == 5) v = fminf(fmaxf(v, -32.f), 32.f);
                if (EPI == 6) v *= SCALE_LOG2;
                out[(size_t)row * N + col] = f2bf(v);
            }
        }
    }
}

// ---------------------------------------------------------------------------
// MFMA windowed self-attention, shuffle-free, max-free softmax.
// 4-wave blocks (reverted from 1-wave: dispatch overhead dominated).
// ---------------------------------------------------------------------------
__launch_bounds__(256)
__global__ void win_attn(const u16* __restrict__ qkv, const u16* __restrict__ vtbuf,
                         const float* __restrict__ bfrag, u16* __restrict__ o,
                         int layer) {
    const int wid = blockIdx.x * 4 + (threadIdx.x >> 6);   // 0..4095
    const int lane = threadIdx.x & 63;
    const int h = wid & 7, win = wid >> 3;
    const int b = win >> 8, wy = (win >> 4) & 15, wx = win & 15;
    const int g = lane >> 4, c = lane & 15;
    const size_t rowbase = (size_t)b * 16384 + (size_t)wy * 8 * 128 + wx * 8;

    s16x8 qf[4], kf[4];
    #pragma unroll
    for (int qt = 0; qt < 4; ++qt) {
        const int t = qt * 16 + c;
        qf[qt] = *(const s16x8*)&qkv[(rowbase + (size_t)(t >> 3) * 128 + (t & 7)) * 768
                                     + h * 32 + g * 8];
    }
    const int kp0 = 8 * (c >> 2) + (c & 3);       // permuted key row for this lane
    #pragma unroll
    for (int kt = 0; kt < 4; ++kt) {
        const int t = (kt >> 1) * 32 + 4 * (kt & 1) + kp0;
        kf[kt] = *(const s16x8*)&qkv[(rowbase + (size_t)(t >> 3) * 128 + (t & 7)) * 768
                                     + 256 + h * 32 + g * 8];
    }

    const float* bb = bfrag + (size_t)((layer * 8 + h) * 16) * 256;
    f32x4 st[4][4];
    #pragma unroll
    for (int kt = 0; kt < 4; ++kt)
        #pragma unroll
        for (int qt = 0; qt < 4; ++qt)
            st[kt][qt] = *(const f32x4*)&bb[(kt * 4 + qt) * 256 + lane * 4];
    #pragma unroll
    for (int kt = 0; kt < 4; ++kt)
        #pragma unroll
        for (int qt = 0; qt < 4; ++qt)
            st[kt][qt] = __builtin_amdgcn_mfma_f32_16x16x32_bf16(
                kf[kt], qf[qt], st[kt][qt], 0, 0, 0);

    float linv[4];
    #pragma unroll
    for (int qt = 0; qt < 4; ++qt) {
        float sum = 0.f;
        #pragma unroll
        for (int kt = 0; kt < 4; ++kt)
            #pragma unroll
            for (int j = 0; j < 4; ++j) {
                const float p = EXP2F(st[kt][qt][j]);
                st[kt][qt][j] = p;
                sum += p;
            }
        sum += __shfl_xor(sum, 16);
        sum += __shfl_xor(sum, 32);
        linv[qt] = 1.f / sum;
    }

    const u16* vb = vtbuf + ((size_t)win * 256 + h * 32) * 64;
    s16x8 vf[2][2];
    #pragma unroll
    for (int dt = 0; dt < 2; ++dt)
        #pragma unroll
        for (int ks = 0; ks < 2; ++ks)
            vf[dt][ks] = *(const s16x8*)&vb[(size_t)(dt * 16 + c) * 64 + ks * 32 + g * 8];

    f32x4 acc[4][2];
    #pragma unroll
    for (int i = 0; i < 4; ++i)
        #pragma unroll
        for (int j = 0; j < 2; ++j) acc[i][j] = f32x4{0.f,0.f,0.f,0.f};

    #pragma unroll
    for (int qt = 0; qt < 4; ++qt) {
        #pragma unroll
        for (int ks = 0; ks < 2; ++ks) {
            u32x4 w;
            w[0] = cvtpk(st[2*ks][qt][0],   st[2*ks][qt][1]);
            w[1] = cvtpk(st[2*ks][qt][2],   st[2*ks][qt][3]);
            w[2] = cvtpk(st[2*ks+1][qt][0], st[2*ks+1][qt][1]);
            w[3] = cvtpk(st[2*ks+1][qt][2], st[2*ks+1][qt][3]);
            const s16x8 pfrag = __builtin_bit_cast(s16x8, w);
            acc[qt][0] = __builtin_amdgcn_mfma_f32_16x16x32_bf16(pfrag, vf[0][ks], acc[qt][0], 0,0,0);
            acc[qt][1] = __builtin_amdgcn_mfma_f32_16x16x32_bf16(pfrag, vf[1][ks], acc[qt][1], 0,0,0);
        }
    }

    #pragma unroll
    for (int qt = 0; qt < 4; ++qt)
        #pragma unroll
        for (int dt = 0; dt < 2; ++dt)
            #pragma unroll
            for (int j = 0; j < 4; ++j) {
                const int t = qt * 16 + g * 4 + j;
                o[(rowbase + (size_t)(t >> 3) * 128 + (t & 7)) * 256
                  + h * 32 + dt * 16 + c] = f2bf(acc[qt][dt][j] * linv[qt]);
            }
}

// ---------------------------------------------------------------------------
// Transpose: xbT[b][c][n] = xb[b][n][c].
// ---------------------------------------------------------------------------
__launch_bounds__(256)
__global__ void tr_kernel(const u16* __restrict__ src, u16* __restrict__ dst) {
    __shared__ u16 T[64][72];
    const int b = blockIdx.z;
    const int n0 = blockIdx.x * 64, c0 = blockIdx.y * 64;
    const int r = threadIdx.x >> 3, cc = (threadIdx.x & 7) * 8;
    const u16* S = src + (size_t)b * 16384 * 256;
    u16* D = dst + (size_t)b * 256 * 16384;
    #pragma unroll
    for (int rr = 0; rr < 64; rr += 32)
        *(u16x8*)&T[r + rr][cc] = *(const u16x8*)&S[(size_t)(n0 + r + rr) * 256 + c0 + cc];
    __syncthreads();
    #pragma unroll
    for (int rr = 0; rr < 64; rr += 32) {
        u16x8 v;
        #pragma unroll
        for (int k2 = 0; k2 < 8; ++k2) v[k2] = T[cc + k2][r + rr];
        *(u16x8*)&D[(size_t)(c0 + r + rr) * 16384 + n0 + cc] = v;
    }
}

// ---------------------------------------------------------------------------
// MFMA flash cross-attention: max-free softmax, denominator via ones-MFMA,
// 128 queries/wave, KSPLIT=32. 1-wave blocks (no LDS, no barriers).
// ---------------------------------------------------------------------------
__launch_bounds__(64)
__global__ void ca_flash(const u16* __restrict__ qb, const u16* __restrict__ xb,
                         const u16* __restrict__ xbT, float* __restrict__ pbuf) {
    const int wid = blockIdx.x;                // 0..2047
    const int lane = threadIdx.x;
    const int ks = wid & 31, qt = (wid >> 5) & 3, h = (wid >> 7) & 7, b = wid >> 10;
    const int g = lane >> 4, c = lane & 15;
    const int kp0 = 8 * (c >> 2) + (c & 3);    // permuted key row for this lane

    s16x8 qf[8];
    #pragma unroll
    for (int nt = 0; nt < 8; ++nt) {
        const int q = qt * 128 + nt * 16 + c;
        qf[nt] = *(const s16x8*)&qb[((size_t)q * 2 + b) * 256 + h * 32 + g * 8];
    }
    const u16* Kb = xb  + (size_t)b * 16384 * 256 + h * 32;
    const u16* Vb = xbT + (size_t)b * 256 * 16384 + (size_t)(h * 32) * 16384;

    s16x8 ones;
    #pragma unroll
    for (int j = 0; j < 8; ++j) ones[j] = (short)0x3F80;   // bf16 1.0

    f32x4 acc[2][8];    // [d-tile][q-subtile]
    f32x4 accl[8];      // denominator rows per q-subtile
    #pragma unroll
    for (int j = 0; j < 8; ++j) {
        acc[0][j] = f32x4{0.f,0.f,0.f,0.f};
        acc[1][j] = f32x4{0.f,0.f,0.f,0.f};
        accl[j]   = f32x4{0.f,0.f,0.f,0.f};
    }

    const int base = ks * 512;
    const f32x4 zero = f32x4{0.f, 0.f, 0.f, 0.f};
    for (int step = 0; step < 16; ++step) {
        const int n0 = base + step * 32;
        const s16x8 kf0 = *(const s16x8*)&Kb[(size_t)(n0 + kp0) * 256 + g * 8];
        const s16x8 kf1 = *(const s16x8*)&Kb[(size_t)(n0 + kp0 + 4) * 256 + g * 8];
        const s16x8 vf0 = *(const s16x8*)&Vb[(size_t)c * 16384 + n0 + g * 8];
        const s16x8 vf1 = *(const s16x8*)&Vb[(size_t)(16 + c) * 16384 + n0 + g * 8];
        #pragma unroll
        for (int nt = 0; nt < 8; ++nt) {
            const f32x4 sa = __builtin_amdgcn_mfma_f32_16x16x32_bf16(kf0, qf[nt], zero, 0, 0, 0);
            const f32x4 sb = __builtin_amdgcn_mfma_f32_16x16x32_bf16(kf1, qf[nt], zero, 0, 0, 0);
            u32x4 w;
            w[0] = cvtpk(EXP2F(sa[0]), EXP2F(sa[1]));
            w[1] = cvtpk(EXP2F(sa[2]), EXP2F(sa[3]));
            w[2] = cvtpk(EXP2F(sb[0]), EXP2F(sb[1]));
            w[3] = cvtpk(EXP2F(sb[2]), EXP2F(sb[3]));
            const s16x8 pf = __builtin_bit_cast(s16x8, w);
            acc[0][nt] = __builtin_amdgcn_mfma_f32_16x16x32_bf16(vf0, pf, acc[0][nt], 0, 0, 0);
            acc[1][nt] = __builtin_amdgcn_mfma_f32_16x16x32_bf16(vf1, pf, acc[1][nt], 0, 0, 0);
            accl[nt]   = __builtin_amdgcn_mfma_f32_16x16x32_bf16(ones, pf, accl[nt], 0, 0, 0);
        }
    }

    // pbuf wave record (4224 f32): [0..127] = l per query, [128..4223] = O^T
    float* P = pbuf + (size_t)wid * 4224;
    if (g == 0) {
        #pragma unroll
        for (int nt = 0; nt < 8; ++nt)
            P[nt * 16 + c] = accl[nt][0];
    }
    #pragma unroll
    for (int mi = 0; mi < 2; ++mi)
        #pragma unroll
        for (int nt = 0; nt < 8; ++nt)
            *(f32x4*)&P[128 + (c + 16*nt) * 32 + 16*mi + g*4] = acc[mi][nt];
}

// ---------------------------------------------------------------------------
// Merge 32 key-split partials: plain sums (no exp, no max).
// ---------------------------------------------------------------------------
__launch_bounds__(256)
__global__ void ca_merge(const float* __restrict__ pbuf, u16* __restrict__ ctx) {
    const int wave = threadIdx.x >> 6, lane = threadIdx.x & 63;
    const int sub = lane >> 5, d = lane & 31;
    const int rowid = blockIdx.x * 8 + wave * 2 + sub;     // 0..8191
    const int t = rowid & 511, h = (rowid >> 9) & 7, b = rowid >> 12;
    const int qt = t >> 7, qq = t & 127;
    const size_t w0 = (size_t)((b * 8 + h) * 4 + qt) * 32;
    float L = 0.f, o = 0.f;
    #pragma unroll
    for (int i = 0; i < 32; ++i) {
        L += pbuf[(w0 + i) * 4224 + qq];
        o += pbuf[(w0 + i) * 4224 + 128 + qq * 32 + d];
    }
    ctx[((size_t)b * 512 + t) * 256 + h * 32 + d] = f2bf(o / L);
}

// ---------------------------------------------------------------------------
// Final: out = LN(query + ctx^T).
// ---------------------------------------------------------------------------
__launch_bounds__(256)
__global__ void final_ln(const float* __restrict__ query, const u16* __restrict__ ctx4,
                         const float* __restrict__ g, const float* __restrict__ b,
                         float* __restrict__ out) {
    const int wave = threadIdx.x >> 6, lane = threadIdx.x & 63;
    const int row = blockIdx.x * 4 + wave;        // 0..1023 = t*2+bb
    const int t = row >> 1, bb = row & 1;
    const int c = lane * 4;
    float4 rq = *(const float4*)(query + (size_t)row * 256 + c);
    u16x4 rc = *(const u16x4*)(ctx4 + ((size_t)bb * 512 + t) * 256 + c);
    float x0 = rq.x + bf2f(rc[0]);
    float x1 = rq.y + bf2f(rc[1]);
    float x2 = rq.z + bf2f(rc[2]);
    float x3 = rq.w + bf2f(rc[3]);
    float s1 = x0 + x1 + x2 + x3;
    float s2 = x0*x0 + x1*x1 + x2*x2 + x3*x3;
    #pragma unroll
    for (int off = 32; off; off >>= 1) {
        s1 += __shfl_xor(s1, off);
        s2 += __shfl_xor(s2, off);
    }
    const float mean = s1 * (1.f/256.f);
    const float var  = s2 * (1.f/256.f) - mean*mean;
    const float rstd = rsqrtf(var + 1e-5f);
    float4 gg = *(const float4*)(g + c);
    float4 bv = *(const float4*)(b + c);
    float4 og;
    og.x = (x0-mean)*rstd*gg.x + bv.x;
    og.y = (x1-mean)*rstd*gg.y + bv.y;
    og.z = (x2-mean)*rstd*gg.z + bv.z;
    og.w = (x3-mean)*rstd*gg.w + bv.w;
    *(float4*)(out + (size_t)row * 256 + c) = og;
}

// ---------------------------------------------------------------------------

extern "C" void kernel_launch(void* const* d_in, const int* in_sizes, int n_in,
                              void* d_out, int out_size, void* d_ws, size_t ws_size,
                              hipStream_t stream) {
    const float* x_in  = (const float*)d_in[0];
    const float* query = (const float*)d_in[1];
    const float* n1_g  = (const float*)d_in[2];
    const float* n1_b  = (const float*)d_in[3];
    const float* qkv_w = (const float*)d_in[4];
    const float* qkv_b = (const float*)d_in[5];
    const float* out_w = (const float*)d_in[6];
    const float* out_b = (const float*)d_in[7];
    const float* rel   = (const float*)d_in[8];
    const float* n2_g  = (const float*)d_in[9];
    const float* n2_b  = (const float*)d_in[10];
    const float* fc1_w = (const float*)d_in[11];
    const float* fc1_b = (const float*)d_in[12];
    const float* fc2_w = (const float*)d_in[13];
    const float* fc2_b = (const float*)d_in[14];
    const float* can_g = (const float*)d_in[15];
    const float* can_b = (const float*)d_in[16];
    const float* cpq_w = (const float*)d_in[17];
    const float* cfc_w = (const float*)d_in[18];
    const float* cfc_b = (const float*)d_in[19];
    const float* cf1_w = (const float*)d_in[20];
    const float* cf1_b = (const float*)d_in[21];
    const float* cf2_w = (const float*)d_in[22];
    const float* cf2_b = (const float*)d_in[23];

    const int M = 32768;   // 2 * 128 * 128 tokens

    char* w = (char*)d_ws;
    float* xs  = (float*)w;  w += (size_t)M * 256 * 4;        // fp32 residual stream
    u16* hbuf  = (u16*)w;    w += (size_t)M * 256 * 2;        // bf16 LN/attn out
    u16* big   = (u16*)w;    w += (size_t)M * 1024 * 2;       // bf16 qkv / mlp hidden
    u16* arena = (u16*)w;    w += (size_t)2228224 * 2;        // bf16 weights + query
    u16* qbuf  = (u16*)w;    w += 524288;
    u16* ctx1  = (u16*)w;    w += 524288;
    u16* ctx2  = (u16*)w;    w += 524288;
    u16* ctx3  = (u16*)w;    w += 1048576;
    u16* ctx4  = (u16*)w;    w += 524288;
    u16* xb    = (u16*)w;    w += (size_t)M * 256 * 2;        // bf16 copy of final xs
    float* bfragb = (float*)w; w += 65536 * 4;                // bias C-fragments

    u16* vtbuf = big + (size_t)M * 768;                       // 16 MB (qkv tail)
    u16*   xbT  = big;                                        // (2,256,16384) 16 MB
    float* pbuf = (float*)(big + 8388608);                    // 2048 * 4224 f32 = 34.6 MB

    u16* wq   = arena;
    u16* wo   = arena + 393216;
    u16* wf1  = arena + 524288;
    u16* wf2  = arena + 1048576;
    u16* wcpq = arena + 1572864;
    u16* wcfc = arena + 1638400;
    u16* wcf1 = arena + 1703936;
    u16* wcf2 = arena + 1835008;
    u16* qcvt = arena + 1966080;

    cvt_weights<<<2176, 256, 0, stream>>>(qkv_w, out_w, fc1_w, fc2_w, cpq_w,
                                          cfc_w, cf1_w, cf2_w, query, arena);
    bias_frag_kernel<<<64, 256, 0, stream>>>(rel, bfragb);

    for (int i = 0; i < 2; ++i) {
        const float* src = (i == 0) ? x_in : xs;   // layer-0 reads input directly
        ln_kernel<<<M/4, 256, 0, stream>>>(src, hbuf, n1_g + i*256, n1_b + i*256, M);
        gemm128<7,false><<<dim3(6,256), 256, 0, stream>>>(
            hbuf, wq + (size_t)i*768*256, qkv_b + i*768, nullptr, big, vtbuf, M, 768, 256);
        win_attn<<<1024, 256, 0, stream>>>(big, vtbuf, bfragb, hbuf, i);
        gemm128<3,true><<<dim3(2,256), 256, 0, stream>>>(
            hbuf, wo + (size_t)i*65536, out_b + i*256, src, xs, nullptr, M, 256, 256);
        ln_kernel<<<M/4, 256, 0, stream>>>(xs, hbuf, n2_g + i*256, n2_b + i*256, M);
        gemm128<2,false><<<dim3(8,256), 256, 0, stream>>>(
            hbuf, wf1 + (size_t)i*262144, fc1_b + i*1024, nullptr, big, nullptr, M, 1024, 256);
        if (i == 0)
            gemm128<3,true><<<dim3(2,256), 256, 0, stream>>>(
                big, wf2, fc2_b, xs, xs, nullptr, M, 256, 1024);
        else
            gemm128<8,true><<<dim3(2,256), 256, 0, stream>>>(
                big, wf2 + 262144, fc2_b + 256, xs, xs, xb, M, 256, 1024);
    }

    // ---- cross-attention ----
    tr_kernel<<<dim3(256, 4, 2), 256, 0, stream>>>(xb, xbT);
    gemm_bt<6><<<dim3(4, 16), 256, 0, stream>>>(qcvt, wcpq, nullptr, qbuf, 1024, 256, 256);
    ca_flash<<<2048, 64, 0, stream>>>(qbuf, xb, xbT, pbuf);
    ca_merge<<<1024, 256, 0, stream>>>(pbuf, ctx1);
    gemm_bt<5><<<dim3(4, 16), 256, 0, stream>>>(ctx1, wcfc, cfc_b, ctx2, 1024, 256, 256);
    gemm_bt<4><<<dim3(8, 16), 256, 0, stream>>>(ctx2, wcf1, cf1_b, ctx3, 1024, 512, 256);
    gemm_bt<1><<<dim3(4, 16), 256, 0, stream>>>(ctx3, wcf2, cf2_b, ctx4, 1024, 256, 512);
    final_ln<<<256, 256, 0, stream>>>(query, ctx4, can_g, can_b, (float*)d_out);

    (void)in_sizes; (void)n_in; (void)out_size; (void)ws_size;
}